// Round 4
// baseline (477.964 us; speedup 1.0000x reference)
//
#include <hip/hip_runtime.h>
#include <stdint.h>

#define D_DIM 512
#define B_ROWS 1024
#define C_ROWS 32768
#define NSPLIT 64             // each gemm block covers 512 n-cols
#define NCHUNK 16             // K chunks of 32

typedef __attribute__((ext_vector_type(8))) short short8;
typedef __attribute__((ext_vector_type(4))) float floatx4;

// fp32 -> bf16 round-to-nearest-even (inputs are well-behaved, no NaN path)
__device__ inline unsigned short f2bf(float f) {
    unsigned u = __float_as_uint(f);
    u += 0x7fffu + ((u >> 16) & 1u);
    return (unsigned short)(u >> 16);
}

// Fragment-major swizzled layout for both normalized matrices:
// 16B unit index ((t16*16 + c)*64 + quad*16 + fr) holds
// row[t16*16 + fr][k = c*32 + quad*8 .. +8]  (bf16 x8).
// A lane (fr=lane&15, quad=lane>>4) then loads its MFMA fragment for
// (t16, c) at unit (t16*16+c)*64 + lane  -> lane-consecutive 16B = perfectly
// coalesced global_load_dwordx4. No LDS, no barriers in the GEMM.

// Normalize rows to norm 3, emit bf16 in fragment-major layout.
// One wave per row; lane covers k = lane*8..+8.
__global__ void norm_swz_kernel(const float* __restrict__ prox,
                                const float* __restrict__ emb,
                                unsigned short* __restrict__ Pbf,
                                unsigned short* __restrict__ Abf) {
    const int wid = threadIdx.x >> 6;
    const int lane = threadIdx.x & 63;
    int row = blockIdx.x * 4 + wid;
    const float* src;
    unsigned short* dst;
    if (row < C_ROWS) {
        src = prox; dst = Pbf;
    } else {
        row -= C_ROWS;
        src = emb; dst = Abf;
    }

    const float4* p = (const float4*)(src + (size_t)row * D_DIM + lane * 8);
    float4 v0 = p[0];
    float4 v1 = p[1];
    float ss = v0.x * v0.x + v0.y * v0.y + v0.z * v0.z + v0.w * v0.w +
               v1.x * v1.x + v1.y * v1.y + v1.z * v1.z + v1.w * v1.w;
#pragma unroll
    for (int off = 1; off < 64; off <<= 1) ss += __shfl_xor(ss, off);
    // norms are ~2.8..23 here, far above the 1e-12 eps in the reference
    const float s = 3.0f * rsqrtf(ss);

    unsigned short h[8];
    h[0] = f2bf(v0.x * s); h[1] = f2bf(v0.y * s);
    h[2] = f2bf(v0.z * s); h[3] = f2bf(v0.w * s);
    h[4] = f2bf(v1.x * s); h[5] = f2bf(v1.y * s);
    h[6] = f2bf(v1.z * s); h[7] = f2bf(v1.w * s);
    uint4 packed;
    packed.x = (unsigned)h[0] | ((unsigned)h[1] << 16);
    packed.y = (unsigned)h[2] | ((unsigned)h[3] << 16);
    packed.z = (unsigned)h[4] | ((unsigned)h[5] << 16);
    packed.w = (unsigned)h[6] | ((unsigned)h[7] << 16);

    // scatter into fragment-major: c = lane>>2, quad = lane&3
    const size_t unit = ((size_t)(row >> 4) * 16 + (lane >> 2)) * 64 +
                        (lane & 3) * 16 + (row & 15);
    *(uint4*)(dst + unit * 8) = packed;
}

// Barrier-free MFMA GEMM with fused exp(2*s) row-sum.
// Block: 128 m-rows x 512 n-cols, 4 waves as 2x2 (wave = 64x64 per 128-tile),
// 2 passes of 2 128-col tiles. A' and B' fragments loaded straight from
// global (coalesced dwordx4), hand-pipelined one K-chunk ahead so the
// compiler emits fine-grained vmcnt waits — no __syncthreads in the K-loop.
__global__ void __launch_bounds__(256, 2)
gemm_lse_kernel(const unsigned short* __restrict__ Ap,
                const unsigned short* __restrict__ Bp,
                float* __restrict__ part) {
    __shared__ float red[128];

    const int tid = threadIdx.x;
    const int wid = tid >> 6;
    const int lane = tid & 63;
    const int m0t = blockIdx.x * 8;     // m tile16 base (128 rows)
    const int n0t = blockIdx.y * 32;    // n tile16 base (512 cols)

    if (tid < 128) red[tid] = 0.f;

    const int wmt = (wid >> 1) * 4;     // wave m offset in t16 units (64 rows)
    const int wnt = (wid & 1) * 4;      // wave n offset in t16 units (64 cols)
    const int fr = lane & 15;
    const int quad = lane >> 4;

    const unsigned short* Abase = Ap + (size_t)(m0t + wmt) * 8192 + lane * 8;

    float rsacc[4][4];
#pragma unroll
    for (int i = 0; i < 4; ++i)
#pragma unroll
        for (int r = 0; r < 4; ++r) rsacc[i][r] = 0.f;

#pragma unroll
    for (int pass = 0; pass < 2; ++pass) {
        const unsigned short* Bbase =
            Bp + (size_t)(n0t + pass * 16 + wnt) * 8192 + lane * 8;

        floatx4 acc[2][4][4];
        const floatx4 zero = {0.f, 0.f, 0.f, 0.f};
#pragma unroll
        for (int tt = 0; tt < 2; ++tt)
#pragma unroll
            for (int i = 0; i < 4; ++i)
#pragma unroll
                for (int j = 0; j < 4; ++j) acc[tt][i][j] = zero;

        short8 abuf[2][4], bbuf[2][2][4];
        // prologue: chunk 0
#pragma unroll
        for (int t = 0; t < 4; ++t)
            abuf[0][t] = *(const short8*)(Abase + t * 8192);
#pragma unroll
        for (int tt = 0; tt < 2; ++tt)
#pragma unroll
            for (int tj = 0; tj < 4; ++tj)
                bbuf[0][tt][tj] = *(const short8*)(Bbase + (tt * 8 + tj) * 8192);

#pragma unroll
        for (int c = 0; c < NCHUNK; ++c) {
            const int cur = c & 1, nxt = cur ^ 1;
            if (c < NCHUNK - 1) {  // prefetch chunk c+1
#pragma unroll
                for (int t = 0; t < 4; ++t)
                    abuf[nxt][t] = *(const short8*)(Abase + t * 8192 + (c + 1) * 512);
#pragma unroll
                for (int tt = 0; tt < 2; ++tt)
#pragma unroll
                    for (int tj = 0; tj < 4; ++tj)
                        bbuf[nxt][tt][tj] =
                            *(const short8*)(Bbase + (tt * 8 + tj) * 8192 + (c + 1) * 512);
            }
#pragma unroll
            for (int ti = 0; ti < 4; ++ti)
#pragma unroll
                for (int tt = 0; tt < 2; ++tt)
#pragma unroll
                    for (int tj = 0; tj < 4; ++tj)
                        acc[tt][ti][tj] = __builtin_amdgcn_mfma_f32_16x16x32_bf16(
                            abuf[cur][ti], bbuf[cur][tt][tj], acc[tt][ti][tj], 0, 0, 0);
        }

        // fold this pass's 256 cols into per-row exp-sums (registers)
#pragma unroll
        for (int ti = 0; ti < 4; ++ti)
#pragma unroll
            for (int tt = 0; tt < 2; ++tt)
#pragma unroll
                for (int tj = 0; tj < 4; ++tj)
#pragma unroll
                    for (int r = 0; r < 4; ++r)
                        rsacc[ti][r] += __expf(2.0f * acc[tt][ti][tj][r]);
    }

    // cross-lane: sum over the 16 col-lanes (bits 0..3), then LDS-combine waves
#pragma unroll
    for (int ti = 0; ti < 4; ++ti) {
#pragma unroll
        for (int r = 0; r < 4; ++r) {
            float v = rsacc[ti][r];
            v += __shfl_xor(v, 1);
            v += __shfl_xor(v, 2);
            v += __shfl_xor(v, 4);
            v += __shfl_xor(v, 8);
            rsacc[ti][r] = v;
        }
    }
    __syncthreads();  // red[] zero-init visible
    if (fr == 0) {
        const int wrow = (wid >> 1) * 64;
#pragma unroll
        for (int ti = 0; ti < 4; ++ti)
#pragma unroll
            for (int r = 0; r < 4; ++r)
                atomicAdd(&red[wrow + ti * 16 + quad * 4 + r], rsacc[ti][r]);
    }
    __syncthreads();
    if (tid < 128)
        part[(size_t)(blockIdx.x * 128 + tid) * NSPLIT + blockIdx.y] = red[tid];
}

// Per-row: sum the 64 partials, positive dot (both arrays fragment-major).
__global__ void rowloss_kernel(const float* __restrict__ part,
                               const unsigned short* __restrict__ A,
                               const unsigned short* __restrict__ Bm,
                               const int* __restrict__ labels,
                               float* __restrict__ rowloss) {
    const int wid = threadIdx.x >> 6;
    const int lane = threadIdx.x & 63;
    const int b = blockIdx.x * 4 + wid;
    if (b >= B_ROWS) return;

    float s = part[(size_t)b * NSPLIT + lane];  // 64 partials, one per lane

    const int l = labels[b];
    const size_t ub_unit = ((size_t)(b >> 4) * 16 + (lane >> 2)) * 64 +
                           (lane & 3) * 16 + (b & 15);
    const size_t ul_unit = ((size_t)(l >> 4) * 16 + (lane >> 2)) * 64 +
                           (lane & 3) * 16 + (l & 15);
    uint4 ua = *(const uint4*)(A + ub_unit * 8);
    uint4 ub = *(const uint4*)(Bm + ul_unit * 8);
    const unsigned* au = (const unsigned*)&ua;
    const unsigned* bu = (const unsigned*)&ub;
    float d = 0.f;
#pragma unroll
    for (int j = 0; j < 4; ++j) {
        float a0 = __uint_as_float(au[j] << 16);
        float a1 = __uint_as_float(au[j] & 0xffff0000u);
        float b0 = __uint_as_float(bu[j] << 16);
        float b1 = __uint_as_float(bu[j] & 0xffff0000u);
        d += a0 * b0 + a1 * b1;
    }
#pragma unroll
    for (int off = 1; off < 64; off <<= 1) {
        s += __shfl_xor(s, off);
        d += __shfl_xor(d, off);
    }
    if (lane == 0) {
        float p2 = 2.0f * d;
        rowloss[b] = logf(s - __expf(p2)) - p2;  // mask positive class
    }
}

__global__ void finalize_kernel(const float* __restrict__ rowloss,
                                float* __restrict__ out) {
    __shared__ float red[4];
    const int tid = threadIdx.x;
    float local = 0.f;
    for (int b = tid; b < B_ROWS; b += 256) local += rowloss[b];
#pragma unroll
    for (int off = 1; off < 64; off <<= 1) local += __shfl_xor(local, off);
    const int wid = tid >> 6;
    const int lane = tid & 63;
    if (lane == 0) red[wid] = local;
    __syncthreads();
    if (tid == 0) out[0] = (red[0] + red[1] + red[2] + red[3]) / (float)B_ROWS;
}

extern "C" void kernel_launch(void* const* d_in, const int* in_sizes, int n_in,
                              void* d_out, int out_size, void* d_ws, size_t ws_size,
                              hipStream_t stream) {
    const float* emb = (const float*)d_in[0];    // [1024, 512]
    const float* prox = (const float*)d_in[1];   // [32768, 512]
    const int* labels = (const int*)d_in[2];     // [1024]
    float* out = (float*)d_out;

    char* ws = (char*)d_ws;
    unsigned short* Pbf = (unsigned short*)ws;                                 // 32 MB
    unsigned short* Abf = (unsigned short*)(ws + (size_t)C_ROWS * D_DIM * 2);  // 1 MB
    float* part = (float*)(ws + (size_t)(C_ROWS + B_ROWS) * D_DIM * 2);        // 256 KB
    float* rowloss = part + (size_t)B_ROWS * NSPLIT;                           // 4 KB

    norm_swz_kernel<<<(C_ROWS + B_ROWS) / 4, 256, 0, stream>>>(prox, emb, Pbf, Abf);
    gemm_lse_kernel<<<dim3(B_ROWS / 128, NSPLIT), 256, 0, stream>>>(Abf, Pbf, part);
    rowloss_kernel<<<B_ROWS / 4, 256, 0, stream>>>(part, Abf, Pbf, labels, rowloss);
    finalize_kernel<<<1, 256, 0, stream>>>(rowloss, out);
}

// Round 5
// 150.035 us; speedup vs baseline: 3.1857x; 3.1857x over previous
//
#include <hip/hip_runtime.h>
#include <stdint.h>

#define D_DIM 512
#define B_ROWS 1024
#define C_ROWS 32768
#define NBLK (C_ROWS / 128)   // 256 n-blocks

typedef __attribute__((ext_vector_type(8))) short short8;
typedef __attribute__((ext_vector_type(4))) float floatx4;

#define GLOBAL_AS __attribute__((address_space(1)))
#define LDS_AS __attribute__((address_space(3)))

// fp32 -> bf16 round-to-nearest-even (inputs are well-behaved, no NaN path)
__device__ inline unsigned short f2bf(float f) {
    unsigned u = __float_as_uint(f);
    u += 0x7fffu + ((u >> 16) & 1u);
    return (unsigned short)(u >> 16);
}

__device__ inline void async_copy16(const unsigned short* g, unsigned short* l) {
    __builtin_amdgcn_global_load_lds((const GLOBAL_AS void*)g, (LDS_AS void*)l, 16, 0, 0);
}

// Normalize rows of BOTH inputs to norm 3, emit bf16 row-major. One wave/row.
// Rows [0, C_ROWS) -> proxies, rows [C_ROWS, C_ROWS+B_ROWS) -> embeddings.
__global__ void norm_rows_kernel(const float* __restrict__ prox,
                                 const float* __restrict__ emb,
                                 unsigned short* __restrict__ Pbf,
                                 unsigned short* __restrict__ Abf) {
    const int wid = threadIdx.x >> 6;
    const int lane = threadIdx.x & 63;
    int row = blockIdx.x * 4 + wid;
    const float* src;
    unsigned short* dst;
    if (row < C_ROWS) {
        src = prox; dst = Pbf;
    } else {
        row -= C_ROWS;
        src = emb; dst = Abf;
    }

    const float4* p = (const float4*)(src + (size_t)row * D_DIM + lane * 8);
    float4 v0 = p[0];
    float4 v1 = p[1];
    float ss = v0.x * v0.x + v0.y * v0.y + v0.z * v0.z + v0.w * v0.w +
               v1.x * v1.x + v1.y * v1.y + v1.z * v1.z + v1.w * v1.w;
#pragma unroll
    for (int off = 1; off < 64; off <<= 1) ss += __shfl_xor(ss, off);
    // norms are ~2.8..23 here, far above the 1e-12 eps in the reference
    const float s = 3.0f * rsqrtf(ss);

    unsigned short h[8];
    h[0] = f2bf(v0.x * s); h[1] = f2bf(v0.y * s);
    h[2] = f2bf(v0.z * s); h[3] = f2bf(v0.w * s);
    h[4] = f2bf(v1.x * s); h[5] = f2bf(v1.y * s);
    h[6] = f2bf(v1.z * s); h[7] = f2bf(v1.w * s);
    uint4 packed;
    packed.x = (unsigned)h[0] | ((unsigned)h[1] << 16);
    packed.y = (unsigned)h[2] | ((unsigned)h[3] << 16);
    packed.z = (unsigned)h[4] | ((unsigned)h[5] << 16);
    packed.w = (unsigned)h[6] | ((unsigned)h[7] << 16);
    *(uint4*)(dst + (size_t)row * D_DIM + lane * 8) = packed;
}

// 128x128 tile bf16 MFMA GEMM over K=512. Depth-2 software pipeline:
// BK=64 chunks double-buffered in LDS; ONE __syncthreads per chunk; the
// prefetch for chunk c+1 is issued right after the barrier and is drained
// only at the NEXT barrier -> the whole ~620-cyc MFMA phase overlaps the
// global->LDS latency. Granule-swizzled LDS (zero ds_read_b128 conflicts).
// Fused exp(2*s) row-sum epilogue; per-block partials, no global atomics.
__global__ void __launch_bounds__(256, 2)
gemm_lse_kernel(const unsigned short* __restrict__ A,
                const unsigned short* __restrict__ Bm,
                float* __restrict__ part) {
    __shared__ unsigned short sA[2][2][128 * 32];  // [dbuf][sub][8 KB]
    __shared__ unsigned short sB[2][2][128 * 32];
    __shared__ float red[128];

    const int tid = threadIdx.x;
    const int wid = tid >> 6;
    const int lane = tid & 63;
    const int n0 = blockIdx.x * 128;   // n-fastest grid: LLC retains B
    const int m0 = blockIdx.y * 128;

    if (tid < 128) red[tid] = 0.f;

    // Staging: HW writes lane's 16B at wave_base + lane*16 == srow*64B + sg*16B.
    // Swizzle: physical granule sg holds logical granule (sg - (srow>>1)) & 3.
    const int srow = wid * 16 + (lane >> 2);                 // 0..63
    const int sg = lane & 3;                                 // physical granule
    const int gl = (sg - ((lane >> 3) & 3)) & 3;             // (srow>>1)&3 == (lane>>3)&3
    const unsigned short* gA = A + (size_t)(m0 + srow) * D_DIM + gl * 8;
    const unsigned short* gB = Bm + (size_t)(n0 + srow) * D_DIM + gl * 8;
    const int loff = srow * 32 + sg * 8;                     // ushort units

    // 2x2 wave arrangement, each wave owns 64x64 via 4x4 MFMA 16x16x32 tiles
    const int wm = (wid >> 1) * 64;
    const int wn = (wid & 1) * 64;
    const int fr = lane & 15;        // A-row / B-col within 16-tile
    const int quad = lane >> 4;      // logical K-granule of this lane's fragment
    const int swz = ((quad + ((fr >> 1) & 3)) & 3) * 8;  // physical granule offset

#define STAGE(d, kk)                                                      \
    do {                                                                  \
        async_copy16(gA + (kk),                   &sA[d][0][loff]);       \
        async_copy16(gA + (kk) + 64 * D_DIM,      &sA[d][0][loff + 64 * 32]); \
        async_copy16(gA + (kk) + 32,              &sA[d][1][loff]);       \
        async_copy16(gA + (kk) + 32 + 64 * D_DIM, &sA[d][1][loff + 64 * 32]); \
        async_copy16(gB + (kk),                   &sB[d][0][loff]);       \
        async_copy16(gB + (kk) + 64 * D_DIM,      &sB[d][0][loff + 64 * 32]); \
        async_copy16(gB + (kk) + 32,              &sB[d][1][loff]);       \
        async_copy16(gB + (kk) + 32 + 64 * D_DIM, &sB[d][1][loff + 64 * 32]); \
    } while (0)

    floatx4 acc[4][4];
    const floatx4 zero = {0.f, 0.f, 0.f, 0.f};
#pragma unroll
    for (int i = 0; i < 4; ++i)
#pragma unroll
        for (int j = 0; j < 4; ++j) acc[i][j] = zero;

    STAGE(0, 0);  // prologue: chunk 0 -> dbuf 0

    for (int c = 0; c < 8; ++c) {
        const int cur = c & 1;
        __syncthreads();  // drains vmcnt(0): chunk c resident; buf[cur^1] free
        if (c < 7) STAGE(cur ^ 1, (c + 1) * 64);  // in flight until next barrier

#pragma unroll
        for (int sub = 0; sub < 2; ++sub) {
            short8 af[4], bfv[4];
#pragma unroll
            for (int t = 0; t < 4; ++t) {
                af[t]  = *(const short8*)&sA[cur][sub][(wm + t * 16 + fr) * 32 + swz];
                bfv[t] = *(const short8*)&sB[cur][sub][(wn + t * 16 + fr) * 32 + swz];
            }
#pragma unroll
            for (int ti = 0; ti < 4; ++ti)
#pragma unroll
                for (int tj = 0; tj < 4; ++tj)
                    acc[ti][tj] = __builtin_amdgcn_mfma_f32_16x16x32_bf16(
                        af[ti], bfv[tj], acc[ti][tj], 0, 0, 0);
        }
    }
#undef STAGE

    // Epilogue: red[m_local] += sum over this block's 128 cols of exp(2*S).
    // C/D layout: col = lane&15, row = quad*4 + reg  [m89/m91-verified]
#pragma unroll
    for (int ti = 0; ti < 4; ++ti) {
        float rs[4] = {0.f, 0.f, 0.f, 0.f};
#pragma unroll
        for (int tj = 0; tj < 4; ++tj)
#pragma unroll
            for (int r = 0; r < 4; ++r)
                rs[r] += __expf(2.0f * acc[ti][tj][r]);
        // sum across the 16 col-lanes (bits 0..3 of lane)
#pragma unroll
        for (int r = 0; r < 4; ++r) {
            rs[r] += __shfl_xor(rs[r], 1);
            rs[r] += __shfl_xor(rs[r], 2);
            rs[r] += __shfl_xor(rs[r], 4);
            rs[r] += __shfl_xor(rs[r], 8);
        }
        if (fr == 0) {
#pragma unroll
            for (int r = 0; r < 4; ++r)
                atomicAdd(&red[wm + ti * 16 + quad * 4 + r], rs[r]);  // LDS atomic
        }
    }
    __syncthreads();
    if (tid < 128) part[(size_t)(m0 + tid) * NBLK + blockIdx.x] = red[tid];
}

// Per-row: sum the 256 partials, compute positive dot, emit per-row loss.
__global__ void rowloss_kernel(const float* __restrict__ part,
                               const unsigned short* __restrict__ A,
                               const unsigned short* __restrict__ Bm,
                               const int* __restrict__ labels,
                               float* __restrict__ rowloss) {
    const int wid = threadIdx.x >> 6;
    const int lane = threadIdx.x & 63;
    const int b = blockIdx.x * 4 + wid;
    if (b >= B_ROWS) return;

    // 256 partials per row, 4 per lane, coalesced float4
    float4 pv = *(const float4*)&part[(size_t)b * NBLK + lane * 4];
    float s = pv.x + pv.y + pv.z + pv.w;

    // positive dot from the bf16 normalized arrays
    const int l = labels[b];
    uint4 ua = *(const uint4*)(A + (size_t)b * D_DIM + lane * 8);
    uint4 ub = *(const uint4*)(Bm + (size_t)l * D_DIM + lane * 8);
    const unsigned* au = (const unsigned*)&ua;
    const unsigned* bu = (const unsigned*)&ub;
    float d = 0.f;
#pragma unroll
    for (int j = 0; j < 4; ++j) {
        float a0 = __uint_as_float(au[j] << 16);
        float a1 = __uint_as_float(au[j] & 0xffff0000u);
        float b0 = __uint_as_float(bu[j] << 16);
        float b1 = __uint_as_float(bu[j] & 0xffff0000u);
        d += a0 * b0 + a1 * b1;
    }
#pragma unroll
    for (int off = 1; off < 64; off <<= 1) {
        s += __shfl_xor(s, off);
        d += __shfl_xor(d, off);
    }
    if (lane == 0) {
        float p2 = 2.0f * d;
        rowloss[b] = logf(s - __expf(p2)) - p2;  // mask positive class
    }
}

__global__ void finalize_kernel(const float* __restrict__ rowloss,
                                float* __restrict__ out) {
    __shared__ float red[4];
    const int tid = threadIdx.x;
    float local = 0.f;
    for (int b = tid; b < B_ROWS; b += 256) local += rowloss[b];
#pragma unroll
    for (int off = 1; off < 64; off <<= 1) local += __shfl_xor(local, off);
    const int wid = tid >> 6;
    const int lane = tid & 63;
    if (lane == 0) red[wid] = local;
    __syncthreads();
    if (tid == 0) out[0] = (red[0] + red[1] + red[2] + red[3]) / (float)B_ROWS;
}

extern "C" void kernel_launch(void* const* d_in, const int* in_sizes, int n_in,
                              void* d_out, int out_size, void* d_ws, size_t ws_size,
                              hipStream_t stream) {
    const float* emb = (const float*)d_in[0];    // [1024, 512]
    const float* prox = (const float*)d_in[1];   // [32768, 512]
    const int* labels = (const int*)d_in[2];     // [1024]
    float* out = (float*)d_out;

    char* ws = (char*)d_ws;
    unsigned short* Pbf = (unsigned short*)ws;                                 // 32 MB
    unsigned short* Abf = (unsigned short*)(ws + (size_t)C_ROWS * D_DIM * 2);  // 1 MB
    float* part = (float*)(ws + (size_t)(C_ROWS + B_ROWS) * D_DIM * 2);        // 1 MB
    float* rowloss = part + (size_t)B_ROWS * NBLK;                             // 4 KB

    norm_rows_kernel<<<(C_ROWS + B_ROWS) / 4, 256, 0, stream>>>(prox, emb, Pbf, Abf);
    gemm_lse_kernel<<<dim3(NBLK, B_ROWS / 128), 256, 0, stream>>>(Abf, Pbf, part);
    rowloss_kernel<<<B_ROWS / 4, 256, 0, stream>>>(part, Abf, Pbf, labels, rowloss);
    finalize_kernel<<<1, 256, 0, stream>>>(rowloss, out);
}

// Round 6
// 142.178 us; speedup vs baseline: 3.3617x; 1.0553x over previous
//
#include <hip/hip_runtime.h>
#include <hip/hip_fp8.h>
#include <stdint.h>

#define D_DIM 512
#define B_ROWS 1024
#define C_ROWS 32768
#define NBLK (C_ROWS / 128)   // 256 n-blocks

typedef __attribute__((ext_vector_type(4))) float floatx4;

#define GLOBAL_AS __attribute__((address_space(1)))
#define LDS_AS __attribute__((address_space(3)))

__device__ inline void async_copy16(const unsigned char* g, unsigned char* l) {
    __builtin_amdgcn_global_load_lds((const GLOBAL_AS void*)g, (LDS_AS void*)l, 16, 0, 0);
}

// OCP e4m3 encode/decode via the HIP type (HW cvt on gfx950)
__device__ inline unsigned char f2fp8(float x) {
    __hip_fp8_e4m3 t(x);
    return t.__x;
}
__device__ inline float fp8tof(unsigned char v) {
    __hip_fp8_e4m3 t;
    t.__x = v;
    return (float)t;
}

// Normalize rows of BOTH inputs to norm 3, emit fp8 e4m3 row-major (512 B/row).
// One wave per row. Block 0 additionally zero-inits rowsum/acc/ticket (stream-
// ordered before the consumers; re-done every call since ws is re-poisoned).
__global__ void norm_rows_kernel(const float* __restrict__ prox,
                                 const float* __restrict__ emb,
                                 unsigned char* __restrict__ Pq,
                                 unsigned char* __restrict__ Aq,
                                 float* __restrict__ rowsum,
                                 float* __restrict__ acc,
                                 unsigned* __restrict__ ticket) {
    if (blockIdx.x == 0) {
        for (int i = threadIdx.x; i < B_ROWS; i += 256) rowsum[i] = 0.f;
        if (threadIdx.x == 0) { *acc = 0.f; *ticket = 0u; }
    }
    const int wid = threadIdx.x >> 6;
    const int lane = threadIdx.x & 63;
    int row = blockIdx.x * 4 + wid;
    const float* src;
    unsigned char* dst;
    if (row < C_ROWS) {
        src = prox; dst = Pq;
    } else {
        row -= C_ROWS;
        src = emb; dst = Aq;
    }

    const float4* p = (const float4*)(src + (size_t)row * D_DIM + lane * 8);
    float4 v0 = p[0];
    float4 v1 = p[1];
    float ss = v0.x * v0.x + v0.y * v0.y + v0.z * v0.z + v0.w * v0.w +
               v1.x * v1.x + v1.y * v1.y + v1.z * v1.z + v1.w * v1.w;
#pragma unroll
    for (int off = 1; off < 64; off <<= 1) ss += __shfl_xor(ss, off);
    // norms are ~2.8..23 here, far above the 1e-12 eps in the reference
    const float s = 3.0f * rsqrtf(ss);

    unsigned char q[8];
    q[0] = f2fp8(v0.x * s); q[1] = f2fp8(v0.y * s);
    q[2] = f2fp8(v0.z * s); q[3] = f2fp8(v0.w * s);
    q[4] = f2fp8(v1.x * s); q[5] = f2fp8(v1.y * s);
    q[6] = f2fp8(v1.z * s); q[7] = f2fp8(v1.w * s);
    uint2 packed;
    packed.x = (unsigned)q[0] | ((unsigned)q[1] << 8) |
               ((unsigned)q[2] << 16) | ((unsigned)q[3] << 24);
    packed.y = (unsigned)q[4] | ((unsigned)q[5] << 8) |
               ((unsigned)q[6] << 16) | ((unsigned)q[7] << 24);
    *(uint2*)(dst + (size_t)row * D_DIM + lane * 8) = packed;
}

// 128x128 tile fp8 MFMA GEMM over K=512, BK=128 (4 barrier-drains per block,
// vs 16 for bf16/BK=32 — fp8 halves bytes so BK=128 fits the same 33 KB LDS).
// Granule swizzle: within a 128 B row, logical 16B-granule g lives at physical
// (g + row) & 7 — spreads ds_read_b64 fragment reads to the 4-cycle LDS floor.
// Epilogue: exp(2*S) row-sums -> LDS -> one global atomicAdd per row.
__global__ void __launch_bounds__(256, 3)
gemm_lse_kernel(const unsigned char* __restrict__ A,
                const unsigned char* __restrict__ Bm,
                float* __restrict__ rowsum) {
    __shared__ unsigned char sA[128 * 128];  // 16 KB (BK=128 fp8)
    __shared__ unsigned char sB[128 * 128];
    __shared__ float red[128];

    const int tid = threadIdx.x;
    const int wid = tid >> 6;
    const int lane = tid & 63;
    const int n0 = blockIdx.x * 128;   // n-fastest grid (round-2: FETCH 60 MB)
    const int m0 = blockIdx.y * 128;

    if (tid < 128) red[tid] = 0.f;

    // Staging: HW writes lane's 16B at wave_base + lane*16. Per call a wave
    // covers 8 rows (lane>>3) x 8 physical granules (lane&7). Since rows per
    // call advance by 8, row&7 == lane>>3 always -> logical granule is hoisted.
    const int r8 = lane >> 3;                     // row mod 8
    const int pg = lane & 7;                      // physical granule
    const int gl = (pg - r8) & 7;                 // logical granule at this slot
    const unsigned char* gA = A + (size_t)(m0 + wid * 32 + r8) * D_DIM + gl * 16;
    const unsigned char* gB = Bm + (size_t)(n0 + wid * 32 + r8) * D_DIM + gl * 16;
    unsigned char* lA = &sA[wid * 32 * 128 + lane * 16];
    unsigned char* lB = &sB[wid * 32 * 128 + lane * 16];

    // 2x2 wave arrangement, each wave owns 64x64 via 4x4 MFMA 16x16x32 tiles
    const int wm = (wid >> 1) * 64;
    const int wn = (wid & 1) * 64;
    const int fr = lane & 15;        // A-row / B-col within 16-tile
    const int quad = lane >> 4;

    floatx4 acc[4][4];
    const floatx4 zero = {0.f, 0.f, 0.f, 0.f};
#pragma unroll
    for (int i = 0; i < 4; ++i)
#pragma unroll
        for (int j = 0; j < 4; ++j) acc[i][j] = zero;

    for (int c = 0; c < 4; ++c) {
        const int kb = c * 128;  // byte offset within the 512 B row
#pragma unroll
        for (int j = 0; j < 4; ++j) {  // 8 rows per call, 32 rows per wave
            async_copy16(gA + kb + j * 8 * D_DIM, lA + j * 8 * 128);
            async_copy16(gB + kb + j * 8 * D_DIM, lB + j * 8 * 128);
        }
        __syncthreads();  // drains vmcnt(0): chunk resident

#pragma unroll
        for (int s = 0; s < 4; ++s) {  // 4 k-steps of 32 within BK=128
            // lane's fragment: row bytes [s*32 + quad*8 .. +8); granule
            // g = 2s + (quad>>1), physical (g + row)&7, row === fr (mod 8)
            const int off = (((2 * s + (quad >> 1) + fr) & 7) * 16) + (quad & 1) * 8;
            long af[4], bf[4];
#pragma unroll
            for (int t = 0; t < 4; ++t) {
                af[t] = *(const long*)&sA[(wm + t * 16 + fr) * 128 + off];
                bf[t] = *(const long*)&sB[(wn + t * 16 + fr) * 128 + off];
            }
#pragma unroll
            for (int ti = 0; ti < 4; ++ti)
#pragma unroll
                for (int tj = 0; tj < 4; ++tj)
                    acc[ti][tj] = __builtin_amdgcn_mfma_f32_16x16x32_fp8_fp8(
                        af[ti], bf[tj], acc[ti][tj], 0, 0, 0);
        }
        __syncthreads();  // protect LDS before next chunk overwrites
    }

    // Epilogue: red[m_local] += sum over this block's 128 cols of exp(2*S).
    // C/D layout: col = lane&15, row = quad*4 + reg (dtype-independent, m121-128)
#pragma unroll
    for (int ti = 0; ti < 4; ++ti) {
        float rs[4] = {0.f, 0.f, 0.f, 0.f};
#pragma unroll
        for (int tj = 0; tj < 4; ++tj)
#pragma unroll
            for (int r = 0; r < 4; ++r)
                rs[r] += __expf(2.0f * acc[ti][tj][r]);
        // sum across the 16 col-lanes (bits 0..3 of lane)
#pragma unroll
        for (int r = 0; r < 4; ++r) {
            rs[r] += __shfl_xor(rs[r], 1);
            rs[r] += __shfl_xor(rs[r], 2);
            rs[r] += __shfl_xor(rs[r], 4);
            rs[r] += __shfl_xor(rs[r], 8);
        }
        if (fr == 0) {
#pragma unroll
            for (int r = 0; r < 4; ++r)
                atomicAdd(&red[wm + ti * 16 + quad * 4 + r], rs[r]);  // LDS atomic
        }
    }
    __syncthreads();
    if (tid < 128) atomicAdd(&rowsum[m0 + tid], red[tid]);  // 256 adds/row total
}

// Fused: per-row positive dot (from the same fp8 data the GEMM saw), row loss,
// block partial sum, grid combine via ticket; last block writes the mean.
__global__ void finalize_kernel(const float* __restrict__ rowsum,
                                const unsigned char* __restrict__ A,
                                const unsigned char* __restrict__ Bm,
                                const int* __restrict__ labels,
                                float* __restrict__ acc,
                                unsigned* __restrict__ ticket,
                                float* __restrict__ out) {
    __shared__ float r4[4];
    const int tid = threadIdx.x;
    const int wid = tid >> 6;
    const int lane = tid & 63;
    const int b = blockIdx.x * 4 + wid;   // grid = 256 blocks, 4 rows each

    const int l = labels[b];
    uint2 ua = *(const uint2*)(A + (size_t)b * D_DIM + lane * 8);
    uint2 ub = *(const uint2*)(Bm + (size_t)l * D_DIM + lane * 8);
    const unsigned char* au = (const unsigned char*)&ua;
    const unsigned char* bu = (const unsigned char*)&ub;
    float d = 0.f;
#pragma unroll
    for (int j = 0; j < 8; ++j) d += fp8tof(au[j]) * fp8tof(bu[j]);
#pragma unroll
    for (int off = 1; off < 64; off <<= 1) d += __shfl_xor(d, off);

    if (lane == 0) {
        float p2 = 2.0f * d;
        r4[wid] = logf(rowsum[b] - __expf(p2)) - p2;  // mask positive class
    }
    __syncthreads();
    if (tid == 0) {
        float bl = r4[0] + r4[1] + r4[2] + r4[3];
        atomicAdd(acc, bl);
        __threadfence();
        unsigned t = atomicAdd(ticket, 1u);
        if (t == 255u) {  // last block: all 256 contributions are in
            float total = atomicAdd(acc, 0.f);  // coherent device-scope read
            out[0] = total / (float)B_ROWS;
        }
    }
}

extern "C" void kernel_launch(void* const* d_in, const int* in_sizes, int n_in,
                              void* d_out, int out_size, void* d_ws, size_t ws_size,
                              hipStream_t stream) {
    const float* emb = (const float*)d_in[0];    // [1024, 512]
    const float* prox = (const float*)d_in[1];   // [32768, 512]
    const int* labels = (const int*)d_in[2];     // [1024]
    float* out = (float*)d_out;

    char* ws = (char*)d_ws;
    unsigned char* Pq = (unsigned char*)ws;                            // 16 MB
    unsigned char* Aq = Pq + (size_t)C_ROWS * D_DIM;                   // 512 KB
    float* rowsum = (float*)(Aq + (size_t)B_ROWS * D_DIM);             // 4 KB
    float* acc = rowsum + B_ROWS;
    unsigned* ticket = (unsigned*)(acc + 1);

    norm_rows_kernel<<<(C_ROWS + B_ROWS) / 4, 256, 0, stream>>>(
        prox, emb, Pq, Aq, rowsum, acc, ticket);
    gemm_lse_kernel<<<dim3(NBLK, B_ROWS / 128), 256, 0, stream>>>(Aq, Pq, rowsum);
    finalize_kernel<<<B_ROWS / 4, 256, 0, stream>>>(
        rowsum, Aq, Pq, labels, acc, ticket, out);
}